// Round 9
// baseline (180.754 us; speedup 1.0000x reference)
//
#include <hip/hip_runtime.h>

// RecurrentCrossLinearAttention: N=16, S=4096, H=16, D=64, M=64, fp32.
// Round 9: r8's verified MFMA pipeline, repacked for occupancy + LDS fix.
//  r8 counters: VALUBusy 15.8, MfmaUtil 2.1, HBM 22%, Occ 20% -> pure
//  latency-bound at 8 waves/CU. Changes:
//   (1) 256-thread (4-wave) blocks, split-S x4, grid 1024 = 4 blocks/CU
//       = 16 waves/CU (LDS exactly 40960 B/block x4 = 160 KiB; VGPR<=128).
//       512-thread blocks provably don't co-schedule (r3: occ stayed 20%).
//   (2) staging stores b32 -> b128 (row-accumulated in regs): r8's 7.4M
//       bank-conflict cycles were the 8-way-conflicted scalar stores;
//       b128 at stride-20 rows is uniform (minimum) like the frag reads.
//  Partials -> d_ws; r3-proven reduce kernel sums split parts + epilogue.
// Numerics: bf16 inputs to MFMA, fp32 acc + fp32 Z (r8: absmax = 1 ulp).

#define S_LEN  4096
#define NHEAD  16
#define DDIM   64
#define MDIM   64
#define NWAVE  4                  // waves per block
#define CH_S   32                 // s-rows per chunk
#define KP32   20                 // u32 per LDS row: 16 data + 4 pad (80 B)
#define WS_ROW 4160               // floats per partial: 64*64 S + 64 z

#define OUT_SOFF  (16 * 16 * 64)
#define OUT_ZOFF  (OUT_SOFF + 16 * 16 * 64 * 64)

using short8 = __attribute__((ext_vector_type(8))) short;
using f32x4  = __attribute__((ext_vector_type(4))) float;
using uint4v = __attribute__((ext_vector_type(4))) unsigned int;

union FragCast { uint4v u; short8 s; };

__device__ __forceinline__ float elup1(float x) {
    // elu(x) + 1 = x+1 (x>0) else exp(x)
    return x > 0.0f ? x + 1.0f : __expf(x);
}

// pack two fp32 -> {lo=bf16(a), hi=bf16(b)} with round-to-nearest-even
__device__ __forceinline__ unsigned bfpack(float a, float b) {
    union { float f; unsigned u; } ca, cb;
    ca.f = a; cb.f = b;
    const unsigned ra = ca.u + 0x7FFFu + ((ca.u >> 16) & 1u);
    const unsigned rb = cb.u + 0x7FFFu + ((cb.u >> 16) & 1u);
    return (ra >> 16) | (rb & 0xFFFF0000u);
}

// hot-loop tiles and merge buffers time-share the same 40960 B of LDS
union SmemT {
    struct {                                   // hot loop: 40960 B
        unsigned Kt[NWAVE][DDIM][KP32];
        unsigned Vt[NWAVE][MDIM][KP32];
    } h;
    struct {                                   // merge: 35328 B
        float buf[2][64][68];
        float zb[2][64];
    } m;
};

__global__ __launch_bounds__(256, 4)           // cap 128 VGPR (r8 used 124)
void rcla_partial(const float* __restrict__ keys,
                  const float* __restrict__ values,
                  const float* __restrict__ kmask,
                  float* __restrict__ ws,
                  int nchk, int psh)
{
    __shared__ SmemT sm;

    const int t    = threadIdx.x;
    const int wave = t >> 6;                   // 0..3
    const int lane = t & 63;
    const int c16  = lane & 15;                // free index (m for A, d for B)
    const int g    = lane >> 4;                // k-group 0..3
    const int part = blockIdx.x & ((1 << psh) - 1);
    const int pair = blockIdx.x >> psh;        // n*16 + h
    const int nIdx = pair >> 4;
    const int hIdx = pair & 15;
    const int d0s  = c16 * 4;                  // 4 consecutive d (or m) staged

    const size_t rowStride = (size_t)NHEAD * DDIM;     // 1024 floats
    const int sWave = part * (S_LEN >> psh) + wave * (nchk * CH_S);
    const size_t base = ((size_t)nIdx * S_LEN + sWave) * rowStride
                      + (size_t)hIdx * DDIM;
    const float* kbase = keys   + base;
    const float* vbase = values + base;
    const float* mbase = kmask + (size_t)nIdx * S_LEN + sWave;

    f32x4 acc[4][4];
#pragma unroll
    for (int i = 0; i < 4; ++i)
#pragma unroll
        for (int j = 0; j < 4; ++j) acc[i][j] = f32x4{0.f, 0.f, 0.f, 0.f};
    float4 zacc = make_float4(0.f, 0.f, 0.f, 0.f);

    for (int ch = 0; ch < nchk; ++ch) {
        const int scg = ch * CH_S + g * 8;     // this lane's first s in chunk
        unsigned kw[16];                       // [row i][col q] -> kw[i*4+q]

        // ---- K phase: 8 rows, elu+mask+z, pack, 4x ds_write_b128 ----
#pragma unroll
        for (int q = 0; q < 4; ++q) {
            const int sl = scg + 2 * q;
            const float* kp = kbase + (size_t)sl * rowStride + d0s;
            const float4 k1 = *(const float4*)kp;
            const float4 k2 = *(const float4*)(kp + rowStride);
            const float2 mm = *(const float2*)(mbase + sl);
            const float a0 = elup1(k1.x) * mm.x, a1 = elup1(k1.y) * mm.x;
            const float a2 = elup1(k1.z) * mm.x, a3 = elup1(k1.w) * mm.x;
            const float b0 = elup1(k2.x) * mm.y, b1 = elup1(k2.y) * mm.y;
            const float b2 = elup1(k2.z) * mm.y, b3 = elup1(k2.w) * mm.y;
            zacc.x += a0 + b0;  zacc.y += a1 + b1;
            zacc.z += a2 + b2;  zacc.w += a3 + b3;
            kw[0 * 4 + q] = bfpack(a0, b0);
            kw[1 * 4 + q] = bfpack(a1, b1);
            kw[2 * 4 + q] = bfpack(a2, b2);
            kw[3 * 4 + q] = bfpack(a3, b3);
        }
#pragma unroll
        for (int i = 0; i < 4; ++i) {
            uint4v w = {kw[i * 4 + 0], kw[i * 4 + 1], kw[i * 4 + 2], kw[i * 4 + 3]};
            *(uint4v*)&sm.h.Kt[wave][d0s + i][g * 4] = w;
        }

        // ---- V phase: 8 rows, pack, 4x ds_write_b128 (reuse kw) ----
#pragma unroll
        for (int q = 0; q < 4; ++q) {
            const int sl = scg + 2 * q;
            const float* vp = vbase + (size_t)sl * rowStride + d0s;
            const float4 v1 = *(const float4*)vp;
            const float4 v2 = *(const float4*)(vp + rowStride);
            kw[0 * 4 + q] = bfpack(v1.x, v2.x);
            kw[1 * 4 + q] = bfpack(v1.y, v2.y);
            kw[2 * 4 + q] = bfpack(v1.z, v2.z);
            kw[3 * 4 + q] = bfpack(v1.w, v2.w);
        }
#pragma unroll
        for (int i = 0; i < 4; ++i) {
            uint4v w = {kw[i * 4 + 0], kw[i * 4 + 1], kw[i * 4 + 2], kw[i * 4 + 3]};
            *(uint4v*)&sm.h.Vt[wave][d0s + i][g * 4] = w;
        }

        // compiler fence: staging stores precede fragment loads
        // (HW: per-wave in-order DS pipe; zero instructions)
        asm volatile("" ::: "memory");

        // ---- fragment loads: 8 consecutive s = u32 cols g*4..g*4+3 ----
        short8 af[4], bff[4];
#pragma unroll
        for (int ti = 0; ti < 4; ++ti) {
            FragCast fc;
            fc.u = *(const uint4v*)&sm.h.Vt[wave][ti * 16 + c16][g * 4];
            af[ti] = fc.s;
        }
#pragma unroll
        for (int tj = 0; tj < 4; ++tj) {
            FragCast fc;
            fc.u = *(const uint4v*)&sm.h.Kt[wave][tj * 16 + c16][g * 4];
            bff[tj] = fc.s;
        }

        asm volatile("" ::: "memory");

        // ---- MFMA: 16 tiles, A = V^T (free=m), B = K (free=d) ----
#pragma unroll
        for (int ti = 0; ti < 4; ++ti)
#pragma unroll
            for (int tj = 0; tj < 4; ++tj)
                acc[ti][tj] = __builtin_amdgcn_mfma_f32_16x16x32_bf16(
                    af[ti], bff[tj], acc[ti][tj], 0, 0, 0);
    }

    // ---- z: sum over the 4 k-groups (lanes xor 16, 32) ----
    zacc.x += __shfl_xor(zacc.x, 16, 64); zacc.y += __shfl_xor(zacc.y, 16, 64);
    zacc.z += __shfl_xor(zacc.z, 16, 64); zacc.w += __shfl_xor(zacc.w, 16, 64);
    zacc.x += __shfl_xor(zacc.x, 32, 64); zacc.y += __shfl_xor(zacc.y, 32, 64);
    zacc.z += __shfl_xor(zacc.z, 32, 64); zacc.w += __shfl_xor(zacc.w, 32, 64);

    __syncthreads();                           // hot LDS dead; reuse as merge

    // ---- merge 4 wave-partials -> 2 buffers, 2 barriered rounds ----
    // D-layout [HW-verified m89]: m = ti*16 + g*4 + reg, d = tj*16 + c16
    const int grp = wave >> 1;
    for (int rr = 0; rr < 2; ++rr) {
        if ((wave & 1) == rr) {
#pragma unroll
            for (int ti = 0; ti < 4; ++ti)
#pragma unroll
                for (int tj = 0; tj < 4; ++tj)
#pragma unroll
                    for (int r = 0; r < 4; ++r) {
                        const int m = ti * 16 + g * 4 + r;
                        const int d = tj * 16 + c16;
                        if (rr == 0) sm.m.buf[grp][m][d]  = acc[ti][tj][r];
                        else         sm.m.buf[grp][m][d] += acc[ti][tj][r];
                    }
            if (lane < 16) {
                if (rr == 0) {
                    sm.m.zb[grp][d0s]     = zacc.x;  sm.m.zb[grp][d0s + 1] = zacc.y;
                    sm.m.zb[grp][d0s + 2] = zacc.z;  sm.m.zb[grp][d0s + 3] = zacc.w;
                } else {
                    sm.m.zb[grp][d0s]     += zacc.x; sm.m.zb[grp][d0s + 1] += zacc.y;
                    sm.m.zb[grp][d0s + 2] += zacc.z; sm.m.zb[grp][d0s + 3] += zacc.w;
                }
            }
        }
        __syncthreads();
    }

    // ---- final 2-way sum -> ws partial ----
    float* wrow = ws + (size_t)blockIdx.x * WS_ROW;
    {
        const int m  = t >> 2;
        const int dc = (t & 3) * 16;
#pragma unroll
        for (int j = 0; j < 16; j += 4) {
            float4 a = *(const float4*)&sm.m.buf[0][m][dc + j];
            const float4 b = *(const float4*)&sm.m.buf[1][m][dc + j];
            a.x += b.x; a.y += b.y; a.z += b.z; a.w += b.w;
            *(float4*)&wrow[m * 64 + dc + j] = a;
        }
    }
    if (t < DDIM) wrow[64 * 64 + t] = sm.m.zb[0][t] + sm.m.zb[1][t];
}

// ---------------- reduce + epilogue kernel ----------------
__global__ __launch_bounds__(256)
void rcla_reduce(const float* __restrict__ query,
                 const float* __restrict__ ws,
                 float* __restrict__ out,
                 int nsplit)
{
    __shared__ float S[64][68];
    __shared__ float zb[64];
    __shared__ float qb[64];

    const int p = blockIdx.x;                  // pair
    const int t = threadIdx.x;
    const float* bp = ws + (size_t)p * nsplit * WS_ROW;

    const int m  = t >> 2;
    const int dc = (t & 3) * 16;
    float4 a[4];
#pragma unroll
    for (int j = 0; j < 4; ++j) a[j] = make_float4(0.f, 0.f, 0.f, 0.f);
    for (int part = 0; part < nsplit; ++part) {
        const float* w = bp + (size_t)part * WS_ROW + m * 64 + dc;
#pragma unroll
        for (int j = 0; j < 4; ++j) {
            const float4 x = *(const float4*)&w[j * 4];
            a[j].x += x.x; a[j].y += x.y; a[j].z += x.z; a[j].w += x.w;
        }
    }
#pragma unroll
    for (int j = 0; j < 4; ++j) {
        *(float4*)&out[OUT_SOFF + (size_t)p * 4096 + m * 64 + dc + j * 4] = a[j];
        *(float4*)&S[m][dc + j * 4] = a[j];
    }
    if (t < 64) {
        float zv = 0.f;
        for (int part = 0; part < nsplit; ++part)
            zv += bp[(size_t)part * WS_ROW + 64 * 64 + t];
        out[OUT_ZOFF + (size_t)p * 64 + t] = zv;
        zb[t] = zv;
        qb[t] = elup1(query[(size_t)p * 64 + t]);
    }
    __syncthreads();

    if (t < 64) {                              // wave 0: V_out
        float zp = qb[t] * zb[t];
#pragma unroll
        for (int off = 32; off >= 1; off >>= 1) zp += __shfl_xor(zp, off, 64);
        const float qz = 1.0f / (zp + 1e-6f);
        float vs = 0.0f;
#pragma unroll
        for (int d = 0; d < 64; d += 4) {
            const float4 sv = *(const float4*)&S[t][d];
            vs = fmaf(qb[d],     sv.x, vs);
            vs = fmaf(qb[d + 1], sv.y, vs);
            vs = fmaf(qb[d + 2], sv.z, vs);
            vs = fmaf(qb[d + 3], sv.w, vs);
        }
        out[(size_t)p * 64 + t] = qz * vs;
    }
}

extern "C" void kernel_launch(void* const* d_in, const int* in_sizes, int n_in,
                              void* d_out, int out_size, void* d_ws, size_t ws_size,
                              hipStream_t stream) {
    const float* q  = (const float*)d_in[0];
    const float* k  = (const float*)d_in[1];
    const float* v  = (const float*)d_in[2];
    const float* km = (const float*)d_in[3];
    float* out = (float*)d_out;
    float* wsf = (float*)d_ws;

    // pick split by workspace: 4 (17.0 MB) > 2 (8.5 MB, r3-proven) > 1
    int psh = 2;
    if (ws_size < (size_t)256 * 4 * WS_ROW * sizeof(float)) psh = 1;
    if (ws_size < (size_t)256 * 2 * WS_ROW * sizeof(float)) psh = 0;
    const int split = 1 << psh;
    const int nchk  = (S_LEN >> psh) / (NWAVE * CH_S);

    rcla_partial<<<dim3(256 * split), dim3(256), 0, stream>>>(k, v, km, wsf, nchk, psh);
    rcla_reduce <<<dim3(256),         dim3(256), 0, stream>>>(q, wsf, out, split);
}

// Round 11
// 131.004 us; speedup vs baseline: 1.3798x; 1.3798x over previous
//
#include <hip/hip_runtime.h>

// RecurrentCrossLinearAttention: N=16, S=4096, H=16, D=64, M=64, fp32.
// Round 11: r10's hot loop (3x S-proven) + 4 blocks/CU packing, with the
// entire r10 post-loop suspect class removed after the Z-only failure
// (lost wave-partial signature, timing-sensitive, r9-pass/r10-fail on
// identical source):
//  - NO union: dedicated u32 hot tile (K/V time-shared per chunk, 20480 B)
//    + dedicated float merge buffer mbuf[64][68] (17408 B). 37888 <= 40960
//    keeps 4 blocks/CU (grid 1024, 256-thr blocks -- r9-proven packing).
//  - NO shfl in partial kernel, NO zb rmw: z written unreduced to private
//    mbuf rows (write-only per lane), then one barriered 16-way sum.
//  - S merge: 4 sequential barriered rmw rounds over mbuf (r1-proven).
// Split-S x4 partials -> d_ws (17 MB tier, r9-proven to fit); reduce
// kernel (r9/r10-proven) sums parts + epilogue.
// launch_bounds: (256) bare. LAW (r2/r4/r9): any min-blocks arg >=4 or
// (1024,1) forces VGPR<=64 -> acc spill. Canary: WRITE_SIZE ~21 MB.

#define S_LEN  4096
#define NHEAD  16
#define DDIM   64
#define MDIM   64
#define NWAVE  4                  // waves per block
#define CH_S   32                 // s-rows per chunk
#define KP32   20                 // u32 per tile row: 16 data + 4 pad (80 B)
#define WS_ROW 4160               // floats per partial: 64*64 S + 64 z

#define OUT_SOFF  (16 * 16 * 64)
#define OUT_ZOFF  (OUT_SOFF + 16 * 16 * 64 * 64)

using short8 = __attribute__((ext_vector_type(8))) short;
using f32x4  = __attribute__((ext_vector_type(4))) float;
using uint4v = __attribute__((ext_vector_type(4))) unsigned int;

union FragCast { uint4v u; short8 s; };

__device__ __forceinline__ float elup1(float x) {
    // elu(x) + 1 = x+1 (x>0) else exp(x)
    return x > 0.0f ? x + 1.0f : __expf(x);
}

// pack two fp32 -> {lo=bf16(a), hi=bf16(b)} with round-to-nearest-even
__device__ __forceinline__ unsigned bfpack(float a, float b) {
    union { float f; unsigned u; } ca, cb;
    ca.f = a; cb.f = b;
    const unsigned ra = ca.u + 0x7FFFu + ((ca.u >> 16) & 1u);
    const unsigned rb = cb.u + 0x7FFFu + ((cb.u >> 16) & 1u);
    return (ra >> 16) | (rb & 0xFFFF0000u);
}

__global__ __launch_bounds__(256)
void rcla_partial(const float* __restrict__ keys,
                  const float* __restrict__ values,
                  const float* __restrict__ kmask,
                  float* __restrict__ ws,
                  int nchk, int psh)
{
    __shared__ unsigned tile[NWAVE][64][KP32];  // 20480 B: K then V, time-shared
    __shared__ float    mbuf[64][68];           // 17408 B: dedicated merge

    const int t    = threadIdx.x;
    const int wave = t >> 6;                    // 0..3
    const int lane = t & 63;
    const int c16  = lane & 15;                 // free index (m for A, d for B)
    const int g    = lane >> 4;                 // k-group 0..3
    const int part = blockIdx.x & ((1 << psh) - 1);
    const int pair = blockIdx.x >> psh;         // n*16 + h
    const int nIdx = pair >> 4;
    const int hIdx = pair & 15;
    const int d0s  = c16 * 4;                   // 4 consecutive d (or m) staged

    const size_t rowStride = (size_t)NHEAD * DDIM;     // 1024 floats
    const int sWave = part * (S_LEN >> psh) + wave * (nchk * CH_S);
    const size_t base = ((size_t)nIdx * S_LEN + sWave) * rowStride
                      + (size_t)hIdx * DDIM;
    const float* kbase = keys   + base;
    const float* vbase = values + base;
    const float* mbase = kmask + (size_t)nIdx * S_LEN + sWave;

    f32x4 acc[4][4];
#pragma unroll
    for (int i = 0; i < 4; ++i)
#pragma unroll
        for (int j = 0; j < 4; ++j) acc[i][j] = f32x4{0.f, 0.f, 0.f, 0.f};
    float z0 = 0.f, z1 = 0.f, z2 = 0.f, z3 = 0.f;   // this lane's d0s..d0s+3

    for (int ch = 0; ch < nchk; ++ch) {
        const int scg = ch * CH_S + g * 8;      // this lane's first s in chunk

        // ---- K phase: 8 rows, elu+mask+z, pack bf16, transposed b32 stores ----
#pragma unroll
        for (int q = 0; q < 4; ++q) {
            const int sp = g * 4 + q;           // u32 column (s-pair index)
            const int sl = scg + 2 * q;         // wave-local s (even)
            const float* kp = kbase + (size_t)sl * rowStride + d0s;
            const float4 k1 = *(const float4*)kp;
            const float4 k2 = *(const float4*)(kp + rowStride);
            const float2 mm = *(const float2*)(mbase + sl);
            const float a0 = elup1(k1.x) * mm.x, a1 = elup1(k1.y) * mm.x;
            const float a2 = elup1(k1.z) * mm.x, a3 = elup1(k1.w) * mm.x;
            const float b0 = elup1(k2.x) * mm.y, b1 = elup1(k2.y) * mm.y;
            const float b2 = elup1(k2.z) * mm.y, b3 = elup1(k2.w) * mm.y;
            z0 += a0 + b0;  z1 += a1 + b1;
            z2 += a2 + b2;  z3 += a3 + b3;
            tile[wave][d0s + 0][sp] = bfpack(a0, b0);
            tile[wave][d0s + 1][sp] = bfpack(a1, b1);
            tile[wave][d0s + 2][sp] = bfpack(a2, b2);
            tile[wave][d0s + 3][sp] = bfpack(a3, b3);
        }

        // fence: K stores precede K fragment reads (per-wave in-order DS pipe)
        asm volatile("" ::: "memory");

        short8 bff[4];                          // B = K, free index d = c16
#pragma unroll
        for (int tj = 0; tj < 4; ++tj) {
            FragCast fc;
            fc.u = *(const uint4v*)&tile[wave][tj * 16 + c16][g * 4];
            bff[tj] = fc.s;
        }

        // fence: K fragment reads precede V stores (read-then-overwrite,
        // r5-proven same-wave DS ordering)
        asm volatile("" ::: "memory");

        // ---- V phase: 8 rows, pack bf16, same tile addresses ----
#pragma unroll
        for (int q = 0; q < 4; ++q) {
            const int sp = g * 4 + q;
            const int sl = scg + 2 * q;
            const float* vp = vbase + (size_t)sl * rowStride + d0s;
            const float4 v1 = *(const float4*)vp;
            const float4 v2 = *(const float4*)(vp + rowStride);
            tile[wave][d0s + 0][sp] = bfpack(v1.x, v2.x);
            tile[wave][d0s + 1][sp] = bfpack(v1.y, v2.y);
            tile[wave][d0s + 2][sp] = bfpack(v1.z, v2.z);
            tile[wave][d0s + 3][sp] = bfpack(v1.w, v2.w);
        }

        asm volatile("" ::: "memory");

        short8 af[4];                           // A = V^T, free index m = c16
#pragma unroll
        for (int ti = 0; ti < 4; ++ti) {
            FragCast fc;
            fc.u = *(const uint4v*)&tile[wave][ti * 16 + c16][g * 4];
            af[ti] = fc.s;
        }

        asm volatile("" ::: "memory");

        // ---- MFMA: 16 tiles of 16x16 over this 32-row chunk ----
#pragma unroll
        for (int ti = 0; ti < 4; ++ti)
#pragma unroll
            for (int tj = 0; tj < 4; ++tj)
                acc[ti][tj] = __builtin_amdgcn_mfma_f32_16x16x32_bf16(
                    af[ti], bff[tj], acc[ti][tj], 0, 0, 0);
    }

    __syncthreads();                            // all waves done with tile

    // ---- S merge: 4 sequential barriered rmw rounds over dedicated mbuf ----
    // D-layout [HW-verified m89]: m = ti*16 + g*4 + reg, d = tj*16 + c16
    for (int rr = 0; rr < 4; ++rr) {
        if (wave == rr) {
#pragma unroll
            for (int ti = 0; ti < 4; ++ti)
#pragma unroll
                for (int tj = 0; tj < 4; ++tj)
#pragma unroll
                    for (int r = 0; r < 4; ++r) {
                        const int m = ti * 16 + g * 4 + r;
                        const int d = tj * 16 + c16;
                        if (rr == 0) mbuf[m][d]  = acc[ti][tj][r];
                        else         mbuf[m][d] += acc[ti][tj][r];
                    }
        }
        __syncthreads();
    }

    // ---- S partial -> ws ----
    float* wrow = ws + (size_t)blockIdx.x * WS_ROW;
    {
        const int m  = t >> 2;
        const int dc = (t & 3) * 16;
#pragma unroll
        for (int j = 0; j < 16; j += 4)
            *(float4*)&wrow[m * 64 + dc + j] = *(const float4*)&mbuf[m][dc + j];
    }
    __syncthreads();                            // S reads done; reuse rows 0..15

    // ---- z: write-only per-(wave,g) rows, then one 16-way sum ----
    mbuf[wave * 4 + g][d0s + 0] = z0;
    mbuf[wave * 4 + g][d0s + 1] = z1;
    mbuf[wave * 4 + g][d0s + 2] = z2;
    mbuf[wave * 4 + g][d0s + 3] = z3;
    __syncthreads();
    if (t < 64) {
        float zv = 0.f;
#pragma unroll
        for (int r = 0; r < 16; ++r) zv += mbuf[r][t];
        wrow[64 * 64 + t] = zv;
    }
}

// ---------------- reduce + epilogue kernel (r9/r10-proven) ----------------
__global__ __launch_bounds__(256)
void rcla_reduce(const float* __restrict__ query,
                 const float* __restrict__ ws,
                 float* __restrict__ out,
                 int nsplit)
{
    __shared__ float S[64][68];
    __shared__ float zb[64];
    __shared__ float qb[64];

    const int p = blockIdx.x;                   // pair
    const int t = threadIdx.x;
    const float* bp = ws + (size_t)p * nsplit * WS_ROW;

    const int m  = t >> 2;
    const int dc = (t & 3) * 16;
    float4 a[4];
#pragma unroll
    for (int j = 0; j < 4; ++j) a[j] = make_float4(0.f, 0.f, 0.f, 0.f);
    for (int part = 0; part < nsplit; ++part) {
        const float* w = bp + (size_t)part * WS_ROW + m * 64 + dc;
#pragma unroll
        for (int j = 0; j < 4; ++j) {
            const float4 x = *(const float4*)&w[j * 4];
            a[j].x += x.x; a[j].y += x.y; a[j].z += x.z; a[j].w += x.w;
        }
    }
#pragma unroll
    for (int j = 0; j < 4; ++j) {
        *(float4*)&out[OUT_SOFF + (size_t)p * 4096 + m * 64 + dc + j * 4] = a[j];
        *(float4*)&S[m][dc + j * 4] = a[j];
    }
    if (t < 64) {
        float zv = 0.f;
        for (int part = 0; part < nsplit; ++part)
            zv += bp[(size_t)part * WS_ROW + 64 * 64 + t];
        out[OUT_ZOFF + (size_t)p * 64 + t] = zv;
        zb[t] = zv;
        qb[t] = elup1(query[(size_t)p * 64 + t]);
    }
    __syncthreads();

    if (t < 64) {                               // wave 0: V_out
        float zp = qb[t] * zb[t];
#pragma unroll
        for (int off = 32; off >= 1; off >>= 1) zp += __shfl_xor(zp, off, 64);
        const float qz = 1.0f / (zp + 1e-6f);
        float vs = 0.0f;
#pragma unroll
        for (int d = 0; d < 64; d += 4) {
            const float4 sv = *(const float4*)&S[t][d];
            vs = fmaf(qb[d],     sv.x, vs);
            vs = fmaf(qb[d + 1], sv.y, vs);
            vs = fmaf(qb[d + 2], sv.z, vs);
            vs = fmaf(qb[d + 3], sv.w, vs);
        }
        out[(size_t)p * 64 + t] = qz * vs;
    }
}

extern "C" void kernel_launch(void* const* d_in, const int* in_sizes, int n_in,
                              void* d_out, int out_size, void* d_ws, size_t ws_size,
                              hipStream_t stream) {
    const float* q  = (const float*)d_in[0];
    const float* k  = (const float*)d_in[1];
    const float* v  = (const float*)d_in[2];
    const float* km = (const float*)d_in[3];
    float* out = (float*)d_out;
    float* wsf = (float*)d_ws;

    // pick split by workspace: 4 (17.0 MB, r9-proven fit) > 2 (8.5 MB) > 1
    int psh = 2;
    if (ws_size < (size_t)256 * 4 * WS_ROW * sizeof(float)) psh = 1;
    if (ws_size < (size_t)256 * 2 * WS_ROW * sizeof(float)) psh = 0;
    const int split = 1 << psh;
    const int nchk  = (S_LEN >> psh) / (NWAVE * CH_S);

    rcla_partial<<<dim3(256 * split), dim3(256), 0, stream>>>(k, v, km, wsf, nchk, psh);
    rcla_reduce <<<dim3(256),         dim3(256), 0, stream>>>(q, wsf, out, split);
}

// Round 12
// 124.134 us; speedup vs baseline: 1.4561x; 1.0553x over previous
//
#include <hip/hip_runtime.h>

// RecurrentCrossLinearAttention: N=16, S=4096, H=16, D=64, M=64, fp32.
// Round 12: DELETE the hot-loop LDS. Key insight: the LDS transpose has
// zero reuse -- each staged element is consumed by exactly one lane's
// fragment (tj,c16 partition d; g partitions s). So each lane loads its
// own fragment elements DIRECTLY from global (16 consecutive dwords per
// 16-lane group = 64B segments; same HBM bytes), elu+packs in registers,
// and MFMAs. No ds_write/ds_read/fences/bank-conflicts; single vmcnt wait
// per chunk; pure-register dataflow the scheduler can pipeline.
// launch_bounds LAW (r2-r11, 5 pts): cap = 256/max(arg2, blockwaves/SIMD):
//   (512,2)->128 (512,4)->64 (256,4)->64 (1024,1)->64 (512,1)->128.
// => (256,1) gives cap 256 safely. 4-wave blocks, split-S x4, grid 1024.
// LDS = 17.4 KB merge only -> never limits blocks/CU.
// Merge/z/ws/reduce = r11-proven (write-only z rows, sequential S rmw).
// Fragment bit-layout identical to r8/r11 (3x-proven D-mapping m89).
// Spill canary: WRITE_SIZE ~17-21 MB, NOT 200+.

#define S_LEN  4096
#define NHEAD  16
#define DDIM   64
#define MDIM   64
#define NWAVE  4                  // waves per block
#define CH_S   32                 // s-rows per chunk (= MFMA k)
#define PITCH  1024               // floats per s row (NHEAD*DDIM)
#define WS_ROW 4160               // floats per partial: 64*64 S + 64 z

#define OUT_SOFF  (16 * 16 * 64)
#define OUT_ZOFF  (OUT_SOFF + 16 * 16 * 64 * 64)

using short8 = __attribute__((ext_vector_type(8))) short;
using f32x4  = __attribute__((ext_vector_type(4))) float;
using uint4v = __attribute__((ext_vector_type(4))) unsigned int;

union FragCast { uint4v u; short8 s; };

__device__ __forceinline__ float elup1(float x) {
    // elu(x) + 1 = x+1 (x>0) else exp(x)
    return x > 0.0f ? x + 1.0f : __expf(x);
}

// pack two fp32 -> {lo=bf16(a), hi=bf16(b)} with round-to-nearest-even
__device__ __forceinline__ unsigned bfpack(float a, float b) {
    union { float f; unsigned u; } ca, cb;
    ca.f = a; cb.f = b;
    const unsigned ra = ca.u + 0x7FFFu + ((ca.u >> 16) & 1u);
    const unsigned rb = cb.u + 0x7FFFu + ((cb.u >> 16) & 1u);
    return (ra >> 16) | (rb & 0xFFFF0000u);
}

// hoist a wave-uniform pointer to SGPRs (HK readfirstlane idiom)
__device__ __forceinline__ const float* rfl_ptr(const float* p) {
    unsigned long long u = (unsigned long long)p;
    const unsigned lo = __builtin_amdgcn_readfirstlane((unsigned)u);
    const unsigned hi = __builtin_amdgcn_readfirstlane((unsigned)(u >> 32));
    return (const float*)(((unsigned long long)hi << 32) | lo);
}

__global__ __launch_bounds__(256, 1)
void rcla_partial(const float* __restrict__ keys,
                  const float* __restrict__ values,
                  const float* __restrict__ kmask,
                  float* __restrict__ ws,
                  int nchk, int psh)
{
    __shared__ float mbuf[64][68];              // 17408 B: merge only

    const int t    = threadIdx.x;
    const int wave = t >> 6;                    // 0..3
    const int lane = t & 63;
    const int c16  = lane & 15;                 // free index (m for A, d for B)
    const int g    = lane >> 4;                 // k-group 0..3 (8 s each)
    const int part = blockIdx.x & ((1 << psh) - 1);
    const int pair = blockIdx.x >> psh;         // n*16 + h
    const int nIdx = pair >> 4;
    const int hIdx = pair & 15;

    const int sWave = part * (S_LEN >> psh) + wave * (nchk * CH_S);
    const size_t base = ((size_t)nIdx * S_LEN + sWave) * PITCH
                      + (size_t)hIdx * DDIM;
    const float* kbase = rfl_ptr(keys   + base) ;
    const float* vbase = rfl_ptr(values + base);
    const float* mbase = rfl_ptr(kmask + (size_t)nIdx * S_LEN + sWave);

    f32x4 acc[4][4];
#pragma unroll
    for (int i = 0; i < 4; ++i)
#pragma unroll
        for (int j = 0; j < 4; ++j) acc[i][j] = f32x4{0.f, 0.f, 0.f, 0.f};
    float zz[4] = {0.f, 0.f, 0.f, 0.f};         // z partial at d = tj*16+c16

    for (int ch = 0; ch < nchk; ++ch) {
        const int s0 = ch * CH_S + g * 8;       // this lane's first s in chunk

        // ---- K: 32 direct transposed dword loads + 8 mask loads ----
        float kraw[4][8];
#pragma unroll
        for (int j = 0; j < 8; ++j) {
            const size_t ro = (size_t)(s0 + j) * PITCH + c16;
#pragma unroll
            for (int tj = 0; tj < 4; ++tj)
                kraw[tj][j] = kbase[ro + tj * 16];
        }
        float mk[8];
#pragma unroll
        for (int j = 0; j < 8; ++j) mk[j] = mbase[s0 + j];

        // ---- V: 32 direct transposed dword loads (independent of K) ----
        float vraw[4][8];
#pragma unroll
        for (int j = 0; j < 8; ++j) {
            const size_t ro = (size_t)(s0 + j) * PITCH + c16;
#pragma unroll
            for (int ti = 0; ti < 4; ++ti)
                vraw[ti][j] = vbase[ro + ti * 16];
        }

        // ---- transform K (elu*mask), accumulate z, pack bf16 ----
        unsigned kf[4][4], vf[4][4];
#pragma unroll
        for (int tj = 0; tj < 4; ++tj)
#pragma unroll
            for (int q = 0; q < 4; ++q) {
                const float e0 = elup1(kraw[tj][2 * q])     * mk[2 * q];
                const float e1 = elup1(kraw[tj][2 * q + 1]) * mk[2 * q + 1];
                zz[tj] += e0 + e1;
                kf[tj][q] = bfpack(e0, e1);
            }
#pragma unroll
        for (int ti = 0; ti < 4; ++ti)
#pragma unroll
            for (int q = 0; q < 4; ++q)
                vf[ti][q] = bfpack(vraw[ti][2 * q], vraw[ti][2 * q + 1]);

        // ---- MFMA: 16 tiles; A = V^T (free=m=c16), B = K (free=d=c16) ----
#pragma unroll
        for (int ti = 0; ti < 4; ++ti) {
            FragCast fa;
            fa.u = uint4v{vf[ti][0], vf[ti][1], vf[ti][2], vf[ti][3]};
#pragma unroll
            for (int tj = 0; tj < 4; ++tj) {
                FragCast fb;
                fb.u = uint4v{kf[tj][0], kf[tj][1], kf[tj][2], kf[tj][3]};
                acc[ti][tj] = __builtin_amdgcn_mfma_f32_16x16x32_bf16(
                    fa.s, fb.s, acc[ti][tj], 0, 0, 0);
            }
        }
    }

    // ---- z: sum over the 4 k-groups (lanes xor 16, 32; r8-proven) ----
#pragma unroll
    for (int tj = 0; tj < 4; ++tj) {
        zz[tj] += __shfl_xor(zz[tj], 16, 64);
        zz[tj] += __shfl_xor(zz[tj], 32, 64);
    }

    __syncthreads();

    // ---- S merge: 4 sequential barriered rmw rounds (r11-proven) ----
    // D-layout [HW-verified m89]: m = ti*16 + g*4 + reg, d = tj*16 + c16
    for (int rr = 0; rr < 4; ++rr) {
        if (wave == rr) {
#pragma unroll
            for (int ti = 0; ti < 4; ++ti)
#pragma unroll
                for (int tj = 0; tj < 4; ++tj)
#pragma unroll
                    for (int r = 0; r < 4; ++r) {
                        const int m = ti * 16 + g * 4 + r;
                        const int d = tj * 16 + c16;
                        if (rr == 0) mbuf[m][d]  = acc[ti][tj][r];
                        else         mbuf[m][d] += acc[ti][tj][r];
                    }
        }
        __syncthreads();
    }

    // ---- S partial -> ws ----
    float* wrow = ws + (size_t)blockIdx.x * WS_ROW;
    {
        const int m  = t >> 2;
        const int dc = (t & 3) * 16;
#pragma unroll
        for (int j = 0; j < 16; j += 4)
            *(float4*)&wrow[m * 64 + dc + j] = *(const float4*)&mbuf[m][dc + j];
    }
    __syncthreads();                            // S reads done; reuse rows 0..3

    // ---- z: write-only per-wave rows (lanes g==0 cover all 64 d), sum ----
    if (g == 0) {
#pragma unroll
        for (int tj = 0; tj < 4; ++tj)
            mbuf[wave][tj * 16 + c16] = zz[tj];
    }
    __syncthreads();
    if (t < 64) {
        float zv = 0.f;
#pragma unroll
        for (int r = 0; r < NWAVE; ++r) zv += mbuf[r][t];
        wrow[64 * 64 + t] = zv;
    }
}

// ---------------- reduce + epilogue kernel (r9/r11-proven) ----------------
__global__ __launch_bounds__(256)
void rcla_reduce(const float* __restrict__ query,
                 const float* __restrict__ ws,
                 float* __restrict__ out,
                 int nsplit)
{
    __shared__ float S[64][68];
    __shared__ float zb[64];
    __shared__ float qb[64];

    const int p = blockIdx.x;                   // pair
    const int t = threadIdx.x;
    const float* bp = ws + (size_t)p * nsplit * WS_ROW;

    const int m  = t >> 2;
    const int dc = (t & 3) * 16;
    float4 a[4];
#pragma unroll
    for (int j = 0; j < 4; ++j) a[j] = make_float4(0.f, 0.f, 0.f, 0.f);
    for (int part = 0; part < nsplit; ++part) {
        const float* w = bp + (size_t)part * WS_ROW + m * 64 + dc;
#pragma unroll
        for (int j = 0; j < 4; ++j) {
            const float4 x = *(const float4*)&w[j * 4];
            a[j].x += x.x; a[j].y += x.y; a[j].z += x.z; a[j].w += x.w;
        }
    }
#pragma unroll
    for (int j = 0; j < 4; ++j) {
        *(float4*)&out[OUT_SOFF + (size_t)p * 4096 + m * 64 + dc + j * 4] = a[j];
        *(float4*)&S[m][dc + j * 4] = a[j];
    }
    if (t < 64) {
        float zv = 0.f;
        for (int part = 0; part < nsplit; ++part)
            zv += bp[(size_t)part * WS_ROW + 64 * 64 + t];
        out[OUT_ZOFF + (size_t)p * 64 + t] = zv;
        zb[t] = zv;
        qb[t] = elup1(query[(size_t)p * 64 + t]);
    }
    __syncthreads();

    if (t < 64) {                               // wave 0: V_out
        float zp = qb[t] * zb[t];
#pragma unroll
        for (int off = 32; off >= 1; off >>= 1) zp += __shfl_xor(zp, off, 64);
        const float qz = 1.0f / (zp + 1e-6f);
        float vs = 0.0f;
#pragma unroll
        for (int d = 0; d < 64; d += 4) {
            const float4 sv = *(const float4*)&S[t][d];
            vs = fmaf(qb[d],     sv.x, vs);
            vs = fmaf(qb[d + 1], sv.y, vs);
            vs = fmaf(qb[d + 2], sv.z, vs);
            vs = fmaf(qb[d + 3], sv.w, vs);
        }
        out[(size_t)p * 64 + t] = qz * vs;
    }
}

extern "C" void kernel_launch(void* const* d_in, const int* in_sizes, int n_in,
                              void* d_out, int out_size, void* d_ws, size_t ws_size,
                              hipStream_t stream) {
    const float* q  = (const float*)d_in[0];
    const float* k  = (const float*)d_in[1];
    const float* v  = (const float*)d_in[2];
    const float* km = (const float*)d_in[3];
    float* out = (float*)d_out;
    float* wsf = (float*)d_ws;

    // pick split by workspace: 4 (17.0 MB) > 2 (8.5 MB) > 1
    int psh = 2;
    if (ws_size < (size_t)256 * 4 * WS_ROW * sizeof(float)) psh = 1;
    if (ws_size < (size_t)256 * 2 * WS_ROW * sizeof(float)) psh = 0;
    const int split = 1 << psh;
    const int nchk  = (S_LEN >> psh) / (NWAVE * CH_S);

    rcla_partial<<<dim3(256 * split), dim3(256), 0, stream>>>(k, v, km, wsf, nchk, psh);
    rcla_reduce <<<dim3(256),         dim3(256), 0, stream>>>(q, wsf, out, split);
}

// Round 14
// 106.284 us; speedup vs baseline: 1.7007x; 1.1679x over previous
//
#include <hip/hip_runtime.h>

// RecurrentCrossLinearAttention: N=16, S=4096, H=16, D=64, M=64, fp32.
// Round 14: r13 + the ONE missing line. r13's V_out and S_state PASSED
// (proving the async global_load_lds + counted-vmcnt stream, the MFMA
// math, and the merge are all correct); only Z failed at 3728 ~ 3/4 of a
// typical Z element: the r12 cross-k-group shuffle reduction of zz[] was
// dropped in the r13 port, so zrows captured only g==0's quarter.
// Restored below; everything else is r13 verbatim.

#define S_LEN  4096
#define NHEAD  16
#define DDIM   64
#define MDIM   64
#define NWAVE  4
#define CH_S   32                 // s-rows per chunk (= MFMA K)
#define NCHK   32                 // chunks per wave: 4096/4/32
#define PITCH  1024               // floats per s row (NHEAD*DDIM)

#define OUT_SOFF  (16 * 16 * 64)
#define OUT_ZOFF  (OUT_SOFF + 16 * 16 * 64 * 64)

using short8 = __attribute__((ext_vector_type(8))) short;
using f32x4  = __attribute__((ext_vector_type(4))) float;
using uint4v = __attribute__((ext_vector_type(4))) unsigned int;

union FragCast { uint4v u; short8 s; };

typedef const __attribute__((address_space(1))) void gvoid_t;
typedef __attribute__((address_space(3))) void lvoid_t;

#define GLOAD16(dst, src) \
    __builtin_amdgcn_global_load_lds((gvoid_t*)(src), (lvoid_t*)(dst), 16, 0, 0)
#define GLOAD4(dst, src) \
    __builtin_amdgcn_global_load_lds((gvoid_t*)(src), (lvoid_t*)(dst), 4, 0, 0)
#define WAITVM17 do { asm volatile("s_waitcnt vmcnt(17)" ::: "memory"); \
                      __builtin_amdgcn_sched_barrier(0); } while (0)
#define WAITVM0  do { asm volatile("s_waitcnt vmcnt(0)"  ::: "memory"); \
                      __builtin_amdgcn_sched_barrier(0); } while (0)

__device__ __forceinline__ float elup1(float x) {
    // elu(x) + 1 = x+1 (x>0) else exp(x)
    return x > 0.0f ? x + 1.0f : __expf(x);
}

// pack two fp32 -> {lo=bf16(a), hi=bf16(b)} with round-to-nearest-even
__device__ __forceinline__ unsigned bfpack(float a, float b) {
    union { float f; unsigned u; } ca, cb;
    ca.f = a; cb.f = b;
    const unsigned ra = ca.u + 0x7FFFu + ((ca.u >> 16) & 1u);
    const unsigned rb = cb.u + 0x7FFFu + ((cb.u >> 16) & 1u);
    return (ra >> 16) | (rb & 0xFFFF0000u);
}

struct WaveBuf {                   // 16640 B
    float K[CH_S][DDIM];
    float V[CH_S][MDIM];
    float mk[64];                  // 32 real + 32 duplicate (no-divergence stage)
};

__global__ __launch_bounds__(256, 1)
void rcla_fused(const float* __restrict__ query,
                const float* __restrict__ keys,
                const float* __restrict__ values,
                const float* __restrict__ kmask,
                float* __restrict__ out)
{
    __shared__ WaveBuf hot[NWAVE][2];          // 133120 B
    __shared__ float mbuf[64][68];             // 17408 B merge / S
    __shared__ float zrows[NWAVE][64];         // 1024 B
    __shared__ float qb[64];
    __shared__ float zb[64];

    const int t    = threadIdx.x;
    const int wave = t >> 6;                   // 0..3
    const int lane = t & 63;
    const int c16  = lane & 15;                // free index (m for A, d for B)
    const int g    = lane >> 4;                // k-group 0..3 (8 s each)
    const int pair = blockIdx.x;               // n*16 + h
    const int nIdx = pair >> 4;
    const int hIdx = pair & 15;

    const int sWave = wave * (NCHK * CH_S);    // 1024 rows per wave
    const size_t base = ((size_t)nIdx * S_LEN + sWave) * PITCH
                      + (size_t)hIdx * DDIM;
    // staging lane map: inst r covers rows r*4..r*4+3; lane -> row r*4+li,
    // cols ci*4..ci*4+3 (lane-contiguous 16B; linear LDS dest)
    const int li = lane >> 4;
    const int ci = lane & 15;
    const float* kl = keys   + base + (size_t)li * PITCH + ci * 4;
    const float* vl = values + base + (size_t)li * PITCH + ci * 4;
    const float* ml = kmask + (size_t)nIdx * S_LEN + sWave + (lane & 31);

    f32x4 acc[4][4];
#pragma unroll
    for (int i = 0; i < 4; ++i)
#pragma unroll
        for (int j = 0; j < 4; ++j) acc[i][j] = f32x4{0.f, 0.f, 0.f, 0.f};
    float zz[4] = {0.f, 0.f, 0.f, 0.f};        // z at d = tj*16 + c16

    auto issue = [&](int p, int ch) {          // 17 VMEM ops
        const size_t co = (size_t)ch * CH_S * PITCH;
        float* Kd = &hot[wave][p].K[0][0];
        float* Vd = &hot[wave][p].V[0][0];
#pragma unroll
        for (int r = 0; r < 8; ++r)
            GLOAD16(Kd + r * 256, kl + co + (size_t)r * 4 * PITCH);
#pragma unroll
        for (int r = 0; r < 8; ++r)
            GLOAD16(Vd + r * 256, vl + co + (size_t)r * 4 * PITCH);
        GLOAD4(&hot[wave][p].mk[0], ml + ch * CH_S);
    };

    auto compute = [&](int p) {
        const WaveBuf& B = hot[wave][p];
        float mk8[8];
#pragma unroll
        for (int j = 0; j < 8; ++j) mk8[j] = B.mk[g * 8 + j];
        float kraw[4][8], vraw[4][8];
#pragma unroll
        for (int tj = 0; tj < 4; ++tj)
#pragma unroll
            for (int j = 0; j < 8; ++j)
                kraw[tj][j] = B.K[g * 8 + j][tj * 16 + c16];
#pragma unroll
        for (int ti = 0; ti < 4; ++ti)
#pragma unroll
            for (int j = 0; j < 8; ++j)
                vraw[ti][j] = B.V[g * 8 + j][ti * 16 + c16];

        unsigned kf[4][4], vf[4][4];
#pragma unroll
        for (int tj = 0; tj < 4; ++tj)
#pragma unroll
            for (int q = 0; q < 4; ++q) {
                const float e0 = elup1(kraw[tj][2 * q])     * mk8[2 * q];
                const float e1 = elup1(kraw[tj][2 * q + 1]) * mk8[2 * q + 1];
                zz[tj] += e0 + e1;
                kf[tj][q] = bfpack(e0, e1);
            }
#pragma unroll
        for (int ti = 0; ti < 4; ++ti)
#pragma unroll
            for (int q = 0; q < 4; ++q)
                vf[ti][q] = bfpack(vraw[ti][2 * q], vraw[ti][2 * q + 1]);

#pragma unroll
        for (int ti = 0; ti < 4; ++ti) {
            FragCast fa;
            fa.u = uint4v{vf[ti][0], vf[ti][1], vf[ti][2], vf[ti][3]};
#pragma unroll
            for (int tj = 0; tj < 4; ++tj) {
                FragCast fb;
                fb.u = uint4v{kf[tj][0], kf[tj][1], kf[tj][2], kf[tj][3]};
                acc[ti][tj] = __builtin_amdgcn_mfma_f32_16x16x32_bf16(
                    fa.s, fb.s, acc[ti][tj], 0, 0, 0);
            }
        }
    };

    // ---- counted-vmcnt double-buffered stream (peeled, static parity) ----
    issue(0, 0);
#pragma unroll 1
    for (int c = 0; c < NCHK - 2; c += 2) {
        issue(1, c + 1);
        WAITVM17;                  // chunk c resident (c+1's 17 in flight)
        compute(0);
        issue(0, c + 2);
        WAITVM17;                  // chunk c+1 resident (c+2's in flight)
        compute(1);
    }
    issue(1, NCHK - 1);
    WAITVM17;
    compute(0);                    // chunk 30
    WAITVM0;
    compute(1);                    // chunk 31

    // ---- z: sum over the 4 k-groups (lanes xor 16, 32) -- THE r13 FIX ----
#pragma unroll
    for (int tj = 0; tj < 4; ++tj) {
        zz[tj] += __shfl_xor(zz[tj], 16, 64);
        zz[tj] += __shfl_xor(zz[tj], 32, 64);
    }

    __syncthreads();               // all waves done streaming

    // ---- S merge: 4 sequential barriered rmw rounds (r11-proven) ----
    // D-layout [HW-verified m89]: m = ti*16 + g*4 + reg, d = tj*16 + c16
    for (int rr = 0; rr < 4; ++rr) {
        if (wave == rr) {
#pragma unroll
            for (int ti = 0; ti < 4; ++ti)
#pragma unroll
                for (int tj = 0; tj < 4; ++tj)
#pragma unroll
                    for (int r = 0; r < 4; ++r) {
                        const int m = ti * 16 + g * 4 + r;
                        const int d = tj * 16 + c16;
                        if (rr == 0) mbuf[m][d]  = acc[ti][tj][r];
                        else         mbuf[m][d] += acc[ti][tj][r];
                    }
        }
        __syncthreads();
    }

    // ---- z rows (write-only, disjoint) + q load ----
    if (g == 0) {
#pragma unroll
        for (int tj = 0; tj < 4; ++tj)
            zrows[wave][tj * 16 + c16] = zz[tj];
    }
    if (t < 64) qb[t] = elup1(query[(size_t)pair * DDIM + t]);

    // ---- S -> out ----
    {
        const int m  = t >> 2;
        const int dc = (t & 3) * 16;
#pragma unroll
        for (int j = 0; j < 16; j += 4)
            *(float4*)&out[OUT_SOFF + (size_t)pair * 4096 + m * 64 + dc + j] =
                *(const float4*)&mbuf[m][dc + j];
    }
    __syncthreads();

    if (t < 64) {
        const float zv = zrows[0][t] + zrows[1][t] + zrows[2][t] + zrows[3][t];
        out[OUT_ZOFF + (size_t)pair * 64 + t] = zv;
        zb[t] = zv;
    }
    __syncthreads();

    // ---- epilogue: wave 0, lane = m (r8-proven) ----
    if (wave == 0) {
        float zp = qb[lane] * zb[lane];
#pragma unroll
        for (int off = 32; off >= 1; off >>= 1) zp += __shfl_xor(zp, off, 64);
        const float qz = 1.0f / (zp + 1e-6f);
        float vs = 0.0f;
#pragma unroll
        for (int d = 0; d < 64; d += 4) {
            const float4 sv = *(const float4*)&mbuf[lane][d];
            vs = fmaf(qb[d],     sv.x, vs);
            vs = fmaf(qb[d + 1], sv.y, vs);
            vs = fmaf(qb[d + 2], sv.z, vs);
            vs = fmaf(qb[d + 3], sv.w, vs);
        }
        out[(size_t)pair * MDIM + lane] = qz * vs;
    }
}

extern "C" void kernel_launch(void* const* d_in, const int* in_sizes, int n_in,
                              void* d_out, int out_size, void* d_ws, size_t ws_size,
                              hipStream_t stream) {
    const float* q  = (const float*)d_in[0];
    const float* k  = (const float*)d_in[1];
    const float* v  = (const float*)d_in[2];
    const float* km = (const float*)d_in[3];
    float* out = (float*)d_out;
    rcla_fused<<<dim3(256), dim3(256), 0, stream>>>(q, k, v, km, out);
}